// Round 1
// baseline (610.687 us; speedup 1.0000x reference)
//
#include <hip/hip_runtime.h>
#include <hip/hip_bf16.h>

#define NATOMS 131072
#define DIM    384
#define NE     4
#define H1N    256
#define H2N    192
#define H3N    160
#define BM     128
#define NTH    512
#define NTILES (NATOMS/BM + NE)   // 1028

typedef __attribute__((ext_vector_type(8))) short bf16x8;
typedef __attribute__((ext_vector_type(4))) float f32x4;
typedef __attribute__((ext_vector_type(4))) int   i32x4;
typedef __attribute__((ext_vector_type(2))) int   i32x2;

// ---------------- ws layout (bytes) ----------------
// meta ints: [0..3]=counts, [4..7]=cursors
#define WS_META   0
#define WS_TABLE  64
#define WS_PERM   (WS_TABLE + NTILES*16)                    // 16512
#define WS_WT1    ((WS_PERM + NATOMS*4 + 255) & ~255)       // 540928
#define SZ_WT1    (NE*H1N*DIM*2)                            // 786432
#define WS_WT2    (WS_WT1 + SZ_WT1)
#define SZ_WT2    (NE*H2N*H1N*2)                            // 393216
#define WS_WT3    (WS_WT2 + SZ_WT2)
#define SZ_WT3    (NE*H3N*H2N*2)                            // 245760

// ---------------- LDS layout (bytes) ----------------
#define L_ROWS 0                       // 128 ints
#define L_X    512                     // 128 rows * 80 B
#define L_W    (L_X + BM*80)           // 10752: 256 rows * 80 B
#define L_H1   (L_W + H1N*80)          // 31232: 128 * 528 B   (also h3: 128*336)
#define L_H2   (L_H1 + BM*528)         // 98816: 128 * 400 B
#define LDS_TOTAL (L_H2 + BM*400)      // 150016

static __device__ __forceinline__ unsigned short f2bf(float f) {
  union { __hip_bfloat16 h; unsigned short u; } v;
  v.h = __float2bfloat16(f);
  return v.u;
}
static __device__ __forceinline__ unsigned pack2(float a, float b) {
  union { __hip_bfloat162 h2; unsigned u; } v;
  v.h2 = __float22bfloat162_rn(make_float2(a, b));
  return v.u;
}
static __device__ __forceinline__ float celu1(float x) {
  return x > 0.f ? x : (__expf(x) - 1.f);
}

// ---------------- prep kernels ----------------
__global__ void k_zero(int* meta) {
  if (threadIdx.x < 16) meta[threadIdx.x] = 0;
}

__global__ void k_wprep(const float* __restrict__ W1, const float* __restrict__ W2,
                        const float* __restrict__ W3,
                        unsigned short* __restrict__ wt1,
                        unsigned short* __restrict__ wt2,
                        unsigned short* __restrict__ wt3) {
  int i = blockIdx.x * 256 + threadIdx.x;
  const int n1 = NE * H1N * DIM;   // 393216
  const int n2 = NE * H2N * H1N;   // 196608
  const int n3 = NE * H3N * H2N;   // 122880
  if (i < n1) {
    int k = i % DIM; int t = i / DIM; int n = t % H1N; int e = t / H1N;
    wt1[i] = f2bf(W1[((size_t)e * DIM + k) * H1N + n]);
  } else if (i < n1 + n2) {
    int j = i - n1;
    int k = j % H1N; int t = j / H1N; int n = t % H2N; int e = t / H2N;
    wt2[j] = f2bf(W2[((size_t)e * H1N + k) * H2N + n]);
  } else if (i < n1 + n2 + n3) {
    int j = i - n1 - n2;
    int k = j % H2N; int t = j / H2N; int n = t % H3N; int e = t / H3N;
    wt3[j] = f2bf(W3[((size_t)e * H2N + k) * H3N + n]);
  }
}

__global__ void k_hist(const int* __restrict__ index, int* __restrict__ meta) {
  int tid = blockIdx.x * blockDim.x + threadIdx.x;
  int lane = threadIdx.x & 63;
  for (int i = tid; i < NATOMS; i += 65536) {
    int e = index[i];
    #pragma unroll
    for (int ex = 0; ex < NE; ++ex) {
      unsigned long long m = __ballot(e == ex);
      if (m && lane == (__ffsll((unsigned long long)m) - 1))
        atomicAdd(&meta[ex], __popcll(m));
    }
  }
}

__global__ void k_plan(int* __restrict__ meta, i32x4* __restrict__ table) {
  __shared__ int off[NE + 1], nt[NE + 1];
  if (threadIdx.x == 0) {
    int o = 0, t = 0;
    for (int e = 0; e < NE; ++e) {
      off[e] = o; nt[e] = t;
      o += meta[e];
      t += (meta[e] + BM - 1) / BM;
      meta[4 + e] = off[e];   // cursor init for scatter
    }
    off[NE] = o; nt[NE] = t;
  }
  __syncthreads();
  for (int i = threadIdx.x; i < NTILES; i += blockDim.x) {
    i32x4 v = {0, 0, 0, 0};
    for (int e = 0; e < NE; ++e) {
      if (i >= nt[e] && i < nt[e + 1]) {
        int local = i - nt[e];
        int cnt = off[e + 1] - off[e];
        int rem = cnt - local * BM;
        v.x = e; v.y = off[e] + local * BM; v.z = rem < BM ? rem : BM;
      }
    }
    table[i] = v;
  }
}

__global__ void k_scatter(const int* __restrict__ index, int* __restrict__ meta,
                          int* __restrict__ perm) {
  int tid = blockIdx.x * blockDim.x + threadIdx.x;
  int lane = threadIdx.x & 63;
  for (int i = tid; i < NATOMS; i += 65536) {
    int e = index[i];
    #pragma unroll
    for (int ex = 0; ex < NE; ++ex) {
      unsigned long long m = __ballot(e == ex);
      if (e == ex) {
        int leader = __ffsll((unsigned long long)m) - 1;
        int before = __popcll(m & ((1ull << lane) - 1ull));
        int base = 0;
        if (lane == leader) base = atomicAdd(&meta[4 + ex], __popcll(m));
        base = __shfl(base, leader);
        perm[base + before] = i;
      }
    }
  }
}

// ---------------- fused MLP ----------------
// Computes y^T = W^T x^T throughout so the D-fragment's 4 regs are 4
// consecutive output-neuron indices (one ds_write_b64 per fragment in the
// epilogue) and both MFMA operands are K-major ds_read_b128.
__launch_bounds__(NTH, 2)
__global__ void k_mlp(const float* __restrict__ aev,
                      const unsigned short* __restrict__ wt1,
                      const unsigned short* __restrict__ wt2,
                      const unsigned short* __restrict__ wt3,
                      const float* __restrict__ b1g,
                      const float* __restrict__ b2g,
                      const float* __restrict__ b3g,
                      const float* __restrict__ w4g,
                      const float* __restrict__ b4g,
                      const float* __restrict__ alpg,
                      const float* __restrict__ shfg,
                      const int* __restrict__ perm,
                      const i32x4* __restrict__ table,
                      float* __restrict__ out)
{
  extern __shared__ char smem[];
  int* ldsRows = (int*)(smem + L_ROWS);

  i32x4 tt = table[blockIdx.x];
  const int e = tt.x, start = tt.y, len = tt.z;
  if (len == 0) return;

  const int tid = threadIdx.x;
  const int l   = tid & 63;
  const int w   = tid >> 6;
  const int l15 = l & 15;
  const int l4o = (l >> 4) * 16;   // byte offset of this lane's k-slice in a 32-elem row
  const int r4  = (l >> 4) * 4;    // D-frag row base (output-neuron offset)

  if (tid < BM) ldsRows[tid] = (tid < len) ? perm[start + tid] : -1;
  __syncthreads();

  const unsigned short* wt1e = wt1 + (size_t)e * H1N * DIM;
  const unsigned short* wt2e = wt2 + (size_t)e * H2N * H1N;
  const unsigned short* wt3e = wt3 + (size_t)e * H3N * H2N;

  // ================= Layer 1: 384 -> 256 =================
  {
    const int wn = (w >> 1) * 64;   // neuron offset (4 waves across n)
    const int wm = (w & 1) * 64;    // atom offset   (2 waves across m)
    f32x4 acc[4][4];
    #pragma unroll
    for (int a = 0; a < 4; ++a)
      #pragma unroll
      for (int b = 0; b < 4; ++b)
        acc[a][b] = f32x4{0.f, 0.f, 0.f, 0.f};

    const int xrow = tid >> 2, xq = tid & 3;
    const int ar = ldsRows[xrow];

    for (int kk = 0; kk < DIM / 32; ++kk) {
      __syncthreads();
      // stage W1 chunk: 256 rows x 32 bf16 (K-major, padded stride 80 B)
      #pragma unroll
      for (int it = 0; it < 2; ++it) {
        int i = tid + it * NTH;
        int row = i >> 2, q = i & 3;
        i32x4 v = *(const i32x4*)(wt1e + (size_t)row * DIM + kk * 32 + q * 8);
        *(i32x4*)(smem + L_W + row * 80 + q * 16) = v;
      }
      // stage X chunk: gather 128 atom rows x 32 fp32 -> bf16
      {
        i32x4 v = {0, 0, 0, 0};
        if (ar >= 0) {
          const float* src = aev + (size_t)ar * DIM + kk * 32 + xq * 8;
          float4 f0 = *(const float4*)(src);
          float4 f1 = *(const float4*)(src + 4);
          v.x = (int)pack2(f0.x, f0.y);
          v.y = (int)pack2(f0.z, f0.w);
          v.z = (int)pack2(f1.x, f1.y);
          v.w = (int)pack2(f1.z, f1.w);
        }
        *(i32x4*)(smem + L_X + xrow * 80 + xq * 16) = v;
      }
      __syncthreads();
      bf16x8 af[4], bx[4];
      #pragma unroll
      for (int ni = 0; ni < 4; ++ni)
        af[ni] = *(const bf16x8*)(smem + L_W + (wn + ni * 16 + l15) * 80 + l4o);
      #pragma unroll
      for (int mi = 0; mi < 4; ++mi)
        bx[mi] = *(const bf16x8*)(smem + L_X + (wm + mi * 16 + l15) * 80 + l4o);
      #pragma unroll
      for (int ni = 0; ni < 4; ++ni)
        #pragma unroll
        for (int mi = 0; mi < 4; ++mi)
          acc[ni][mi] = __builtin_amdgcn_mfma_f32_16x16x32_bf16(af[ni], bx[mi], acc[ni][mi], 0, 0, 0);
    }
    // epilogue: bias + celu -> h1 (K-major [m][n], stride 528 B)
    #pragma unroll
    for (int ni = 0; ni < 4; ++ni) {
      int nb = wn + ni * 16 + r4;
      float4 bias = *(const float4*)(b1g + e * H1N + nb);
      #pragma unroll
      for (int mi = 0; mi < 4; ++mi) {
        int m = wm + mi * 16 + l15;
        f32x4 v = acc[ni][mi];
        i32x2 p;
        p.x = (int)pack2(celu1(v.x + bias.x), celu1(v.y + bias.y));
        p.y = (int)pack2(celu1(v.z + bias.z), celu1(v.w + bias.w));
        *(i32x2*)(smem + L_H1 + m * 528 + nb * 2) = p;
      }
    }
  }

  // ================= Layer 2: 256 -> 192 =================
  {
    const int wn = (w >> 1) * 48;
    const int wm = (w & 1) * 64;
    f32x4 acc[3][4];
    #pragma unroll
    for (int a = 0; a < 3; ++a)
      #pragma unroll
      for (int b = 0; b < 4; ++b)
        acc[a][b] = f32x4{0.f, 0.f, 0.f, 0.f};

    for (int kk = 0; kk < H1N / 32; ++kk) {
      __syncthreads();
      for (int i = tid; i < H2N * 4; i += NTH) {
        int row = i >> 2, q = i & 3;
        i32x4 v = *(const i32x4*)(wt2e + (size_t)row * H1N + kk * 32 + q * 8);
        *(i32x4*)(smem + L_W + row * 80 + q * 16) = v;
      }
      __syncthreads();
      bf16x8 af[3], bx[4];
      #pragma unroll
      for (int ni = 0; ni < 3; ++ni)
        af[ni] = *(const bf16x8*)(smem + L_W + (wn + ni * 16 + l15) * 80 + l4o);
      #pragma unroll
      for (int mi = 0; mi < 4; ++mi)
        bx[mi] = *(const bf16x8*)(smem + L_H1 + (wm + mi * 16 + l15) * 528 + kk * 64 + l4o);
      #pragma unroll
      for (int ni = 0; ni < 3; ++ni)
        #pragma unroll
        for (int mi = 0; mi < 4; ++mi)
          acc[ni][mi] = __builtin_amdgcn_mfma_f32_16x16x32_bf16(af[ni], bx[mi], acc[ni][mi], 0, 0, 0);
    }
    #pragma unroll
    for (int ni = 0; ni < 3; ++ni) {
      int nb = wn + ni * 16 + r4;
      float4 bias = *(const float4*)(b2g + e * H2N + nb);
      #pragma unroll
      for (int mi = 0; mi < 4; ++mi) {
        int m = wm + mi * 16 + l15;
        f32x4 v = acc[ni][mi];
        i32x2 p;
        p.x = (int)pack2(celu1(v.x + bias.x), celu1(v.y + bias.y));
        p.y = (int)pack2(celu1(v.z + bias.z), celu1(v.w + bias.w));
        *(i32x2*)(smem + L_H2 + m * 400 + nb * 2) = p;
      }
    }
  }

  // ================= Layer 3: 192 -> 160 =================
  {
    const int wn = (w >> 2) * 80;   // 2 waves across n (5 frags each)
    const int wm = (w & 3) * 32;    // 4 waves across m (2 frags each)
    f32x4 acc[5][2];
    #pragma unroll
    for (int a = 0; a < 5; ++a)
      #pragma unroll
      for (int b = 0; b < 2; ++b)
        acc[a][b] = f32x4{0.f, 0.f, 0.f, 0.f};

    for (int kk = 0; kk < H2N / 32; ++kk) {
      __syncthreads();
      for (int i = tid; i < H3N * 4; i += NTH) {
        int row = i >> 2, q = i & 3;
        i32x4 v = *(const i32x4*)(wt3e + (size_t)row * H2N + kk * 32 + q * 8);
        *(i32x4*)(smem + L_W + row * 80 + q * 16) = v;
      }
      __syncthreads();
      bf16x8 af[5], bx[2];
      #pragma unroll
      for (int ni = 0; ni < 5; ++ni)
        af[ni] = *(const bf16x8*)(smem + L_W + (wn + ni * 16 + l15) * 80 + l4o);
      #pragma unroll
      for (int mi = 0; mi < 2; ++mi)
        bx[mi] = *(const bf16x8*)(smem + L_H2 + (wm + mi * 16 + l15) * 400 + kk * 64 + l4o);
      #pragma unroll
      for (int ni = 0; ni < 5; ++ni)
        #pragma unroll
        for (int mi = 0; mi < 2; ++mi)
          acc[ni][mi] = __builtin_amdgcn_mfma_f32_16x16x32_bf16(af[ni], bx[mi], acc[ni][mi], 0, 0, 0);
    }
    // epilogue -> h3 in the (now-free) H1 region, stride 336 B
    #pragma unroll
    for (int ni = 0; ni < 5; ++ni) {
      int nb = wn + ni * 16 + r4;
      float4 bias = *(const float4*)(b3g + e * H3N + nb);
      #pragma unroll
      for (int mi = 0; mi < 2; ++mi) {
        int m = wm + mi * 16 + l15;
        f32x4 v = acc[ni][mi];
        i32x2 p;
        p.x = (int)pack2(celu1(v.x + bias.x), celu1(v.y + bias.y));
        p.y = (int)pack2(celu1(v.z + bias.z), celu1(v.w + bias.w));
        *(i32x2*)(smem + L_H1 + m * 336 + nb * 2) = p;
      }
    }
  }
  __syncthreads();

  // ================= Layer 4: 160 -> 1 (VALU) =================
  {
    const int m = tid >> 2, sub = tid & 3;   // 4 lanes per atom
    const char* hp = smem + L_H1 + m * 336 + sub * 80;
    const float* wp = w4g + e * H3N + sub * 40;
    float s = 0.f;
    #pragma unroll
    for (int j = 0; j < 5; ++j) {
      i32x4 hv = *(const i32x4*)(hp + j * 16);
      float4 w0 = *(const float4*)(wp + j * 8);
      float4 w1 = *(const float4*)(wp + j * 8 + 4);
      s += __uint_as_float(((unsigned)hv.x) << 16) * w0.x;
      s += __uint_as_float(((unsigned)hv.x) & 0xffff0000u) * w0.y;
      s += __uint_as_float(((unsigned)hv.y) << 16) * w0.z;
      s += __uint_as_float(((unsigned)hv.y) & 0xffff0000u) * w0.w;
      s += __uint_as_float(((unsigned)hv.z) << 16) * w1.x;
      s += __uint_as_float(((unsigned)hv.z) & 0xffff0000u) * w1.y;
      s += __uint_as_float(((unsigned)hv.w) << 16) * w1.z;
      s += __uint_as_float(((unsigned)hv.w) & 0xffff0000u) * w1.w;
    }
    s += __shfl_xor(s, 1);
    s += __shfl_xor(s, 2);
    if (sub == 0 && m < len) {
      float y = (s + b4g[e]) * alpg[e] + shfg[e];
      out[ldsRows[m]] = y;
    }
  }
}

extern "C" void kernel_launch(void* const* d_in, const int* in_sizes, int n_in,
                              void* d_out, int out_size, void* d_ws, size_t ws_size,
                              hipStream_t stream) {
  (void)in_sizes; (void)n_in; (void)out_size; (void)ws_size;
  const float* aev    = (const float*)d_in[0];
  const int*   index  = (const int*)d_in[1];
  const float* W1     = (const float*)d_in[2];
  const float* b1     = (const float*)d_in[3];
  const float* W2     = (const float*)d_in[4];
  const float* b2     = (const float*)d_in[5];
  const float* W3     = (const float*)d_in[6];
  const float* b3     = (const float*)d_in[7];
  const float* W4     = (const float*)d_in[8];
  const float* b4     = (const float*)d_in[9];
  const float* alphas = (const float*)d_in[10];
  const float* shifts = (const float*)d_in[11];
  float* out = (float*)d_out;
  char* ws = (char*)d_ws;

  int*   meta  = (int*)(ws + WS_META);
  i32x4* table = (i32x4*)(ws + WS_TABLE);
  int*   perm  = (int*)(ws + WS_PERM);
  unsigned short* wt1 = (unsigned short*)(ws + WS_WT1);
  unsigned short* wt2 = (unsigned short*)(ws + WS_WT2);
  unsigned short* wt3 = (unsigned short*)(ws + WS_WT3);

  // allow >64KB dynamic LDS (idempotent; not a stream op, capture-safe)
  hipFuncSetAttribute((const void*)k_mlp,
                      hipFuncAttributeMaxDynamicSharedMemorySize, LDS_TOTAL);

  k_zero<<<1, 64, 0, stream>>>(meta);
  k_wprep<<<(NE*(H1N*DIM + H2N*H1N + H3N*H2N) + 255) / 256, 256, 0, stream>>>(
      W1, W2, W3, wt1, wt2, wt3);
  k_hist<<<256, 256, 0, stream>>>(index, meta);
  k_plan<<<1, 256, 0, stream>>>(meta, table);
  k_scatter<<<256, 256, 0, stream>>>(index, meta, perm);
  k_mlp<<<NTILES, NTH, LDS_TOTAL, stream>>>(
      aev, wt1, wt2, wt3, b1, b2, b3, W4, b4, alphas, shifts, perm, table, out);
}

// Round 2
// 529.147 us; speedup vs baseline: 1.1541x; 1.1541x over previous
//
#include <hip/hip_runtime.h>
#include <hip/hip_bf16.h>

#define NATOMS 131072
#define DIM    384
#define NE     4
#define H1N    256
#define H2N    192
#define H3N    160
#define BM     128
#define NTH    512
#define NTILES (NATOMS/BM + NE)   // 1028

typedef __attribute__((ext_vector_type(8))) short bf16x8;
typedef __attribute__((ext_vector_type(4))) float f32x4;
typedef __attribute__((ext_vector_type(4))) int   i32x4;
typedef __attribute__((ext_vector_type(2))) int   i32x2;

// ---------------- ws layout (bytes) ----------------
#define WS_META   0
#define WS_TABLE  64
#define WS_PERM   (WS_TABLE + NTILES*16)
#define WS_WT1    ((WS_PERM + NATOMS*4 + 255) & ~255)
#define SZ_WT1    (NE*H1N*DIM*2)
#define WS_WT2    (WS_WT1 + SZ_WT1)
#define SZ_WT2    (NE*H2N*H1N*2)
#define WS_WT3    (WS_WT2 + SZ_WT2)
#define SZ_WT3    (NE*H3N*H2N*2)

// ---------------- LDS layout (bytes) ----------------
// W rows padded to 72 B (32 bf16 + 8 pad): read stride 18 banks -> 16
// distinct banks across l15 -> conflict-free ds_read_b128.
#define L_ROWS 0                        // 512 B
#define L_W    512
#define L_WBUF (256*72)                 // 18432, double-buffered
#define L_H1   (L_W + 2*L_WBUF)         // 37376: 128 x 528 B (also h3: 128x336)
#define L_H2   (L_H1 + BM*528)          // 104960: 128 x 400 B
#define LDS_TOTAL (L_H2 + BM*400)       // 156160 <= 160 KiB

static __device__ __forceinline__ unsigned short f2bf(float f) {
  union { __hip_bfloat16 h; unsigned short u; } v;
  v.h = __float2bfloat16(f);
  return v.u;
}
static __device__ __forceinline__ unsigned pack2(float a, float b) {
  union { __hip_bfloat162 h2; unsigned u; } v;
  v.h2 = __float22bfloat162_rn(make_float2(a, b));
  return v.u;
}
static __device__ __forceinline__ float celu1(float x) {
  return x > 0.f ? x : (__expf(x) - 1.f);
}
static __device__ __forceinline__ i32x4 ld16(const unsigned short* p) {
  return *(const i32x4*)p;
}
static __device__ __forceinline__ bf16x8 cvt8(f32x4 a, f32x4 b) {
  union { bf16x8 v; unsigned u[4]; } r;
  r.u[0] = pack2(a.x, a.y); r.u[1] = pack2(a.z, a.w);
  r.u[2] = pack2(b.x, b.y); r.u[3] = pack2(b.z, b.w);
  return r.v;
}

// ---------------- prep kernels ----------------
__global__ void k_zero(int* meta) {
  if (threadIdx.x < 16) meta[threadIdx.x] = 0;
}

__global__ void k_wprep(const float* __restrict__ W1, const float* __restrict__ W2,
                        const float* __restrict__ W3,
                        unsigned short* __restrict__ wt1,
                        unsigned short* __restrict__ wt2,
                        unsigned short* __restrict__ wt3) {
  int i = blockIdx.x * 256 + threadIdx.x;
  const int n1 = NE * H1N * DIM;
  const int n2 = NE * H2N * H1N;
  const int n3 = NE * H3N * H2N;
  if (i < n1) {
    int k = i % DIM; int t = i / DIM; int n = t % H1N; int e = t / H1N;
    wt1[i] = f2bf(W1[((size_t)e * DIM + k) * H1N + n]);
  } else if (i < n1 + n2) {
    int j = i - n1;
    int k = j % H1N; int t = j / H1N; int n = t % H2N; int e = t / H2N;
    wt2[j] = f2bf(W2[((size_t)e * H1N + k) * H2N + n]);
  } else if (i < n1 + n2 + n3) {
    int j = i - n1 - n2;
    int k = j % H2N; int t = j / H2N; int n = t % H3N; int e = t / H3N;
    wt3[j] = f2bf(W3[((size_t)e * H2N + k) * H3N + n]);
  }
}

// block-aggregated histogram: 512 global atomics total (was 8192 contended)
__global__ void k_hist(const int* __restrict__ index, int* __restrict__ meta) {
  __shared__ int h[NE];
  int t = threadIdx.x;
  if (t < NE) h[t] = 0;
  __syncthreads();
  int b0 = blockIdx.x * 1024;
  #pragma unroll
  for (int j = 0; j < 4; ++j) atomicAdd(&h[index[b0 + t + j*256]], 1);
  __syncthreads();
  if (t < NE) atomicAdd(&meta[t], h[t]);
}

__global__ void k_plan(int* __restrict__ meta, i32x4* __restrict__ table) {
  __shared__ int off[NE + 1], nt[NE + 1];
  if (threadIdx.x == 0) {
    int o = 0, t = 0;
    for (int e = 0; e < NE; ++e) {
      off[e] = o; nt[e] = t;
      o += meta[e];
      t += (meta[e] + BM - 1) / BM;
      meta[4 + e] = off[e];
    }
    off[NE] = o; nt[NE] = t;
  }
  __syncthreads();
  for (int i = threadIdx.x; i < NTILES; i += blockDim.x) {
    i32x4 v = {0, 0, 0, 0};
    for (int e = 0; e < NE; ++e) {
      if (i >= nt[e] && i < nt[e + 1]) {
        int local = i - nt[e];
        int cnt = off[e + 1] - off[e];
        int rem = cnt - local * BM;
        v.x = e; v.y = off[e] + local * BM; v.z = rem < BM ? rem : BM;
      }
    }
    table[i] = v;
  }
}

// block-aggregated scatter: one range-reservation atomic per expert per block
__global__ void k_scatter(const int* __restrict__ index, int* __restrict__ meta,
                          int* __restrict__ perm) {
  __shared__ int h[NE], base[NE];
  int t = threadIdx.x;
  if (t < NE) h[t] = 0;
  __syncthreads();
  int b0 = blockIdx.x * 1024;
  int eIdx[4];
  #pragma unroll
  for (int j = 0; j < 4; ++j) {
    eIdx[j] = index[b0 + t + j*256];
    atomicAdd(&h[eIdx[j]], 1);
  }
  __syncthreads();
  if (t < NE) { base[t] = atomicAdd(&meta[4 + t], h[t]); h[t] = 0; }
  __syncthreads();
  #pragma unroll
  for (int j = 0; j < 4; ++j) {
    int e = eIdx[j];
    int slot = atomicAdd(&h[e], 1);
    perm[base[e] + slot] = b0 + t + j*256;
  }
}

// ---------------- fused MLP ----------------
// y^T = W^T x^T throughout. 8 waves = 2 n-groups x 4 m-groups.
// Pipeline per K-step: cvt X(kk) [prefetched 2 ahead] -> ds_read W(buf kk&1)
// -> 16 MFMA -> ds_write W(kk+1) [prefetched 1 ahead] -> barrier.
__launch_bounds__(NTH, 2)
__global__ void k_mlp(const float* __restrict__ aev,
                      const unsigned short* __restrict__ wt1,
                      const unsigned short* __restrict__ wt2,
                      const unsigned short* __restrict__ wt3,
                      const float* __restrict__ b1g,
                      const float* __restrict__ b2g,
                      const float* __restrict__ b3g,
                      const float* __restrict__ w4g,
                      const float* __restrict__ b4g,
                      const float* __restrict__ alpg,
                      const float* __restrict__ shfg,
                      const int* __restrict__ perm,
                      const i32x4* __restrict__ table,
                      float* __restrict__ out)
{
  extern __shared__ char smem[];
  int* ldsRows = (int*)(smem + L_ROWS);

  i32x4 tt = table[blockIdx.x];
  const int e = tt.x, start = tt.y, len = tt.z;
  if (len == 0) return;

  const int tid = threadIdx.x;
  const int l   = tid & 63;
  const int w   = tid >> 6;
  const int l15 = l & 15;
  const int lg  = l >> 4;
  const int l4o = lg * 16;
  const int r4  = lg * 4;
  const int wn  = w & 1;    // 2 n-groups
  const int wm  = w >> 1;   // 4 m-groups (32 atoms each)

  if (tid < BM) ldsRows[tid] = (tid < len) ? perm[start + tid] : -1;
  __syncthreads();

  // per-lane aev row pointers for this wave's 2 m-fragments
  const float* xp[2];
  #pragma unroll
  for (int mi = 0; mi < 2; ++mi) {
    int ar = ldsRows[wm * 32 + mi * 16 + l15];
    xp[mi] = aev + (size_t)(ar < 0 ? 0 : ar) * DIM + lg * 8;
  }

  const unsigned short* wt1e = wt1 + (size_t)e * H1N * DIM;
  const unsigned short* wt2e = wt2 + (size_t)e * H2N * H1N;
  const unsigned short* wt3e = wt3 + (size_t)e * H3N * H2N;

  const int r0 = tid >> 2, q0 = tid & 3;
  const int wl0 = L_W + r0 * 72 + q0 * 16;
  const int wl1 = wl0 + 128 * 72;

  // ================= Layer 1: 384 -> 256 =================
  {
    f32x4 acc[8][2];
    #pragma unroll
    for (int a = 0; a < 8; ++a)
      #pragma unroll
      for (int b = 0; b < 2; ++b)
        acc[a][b] = f32x4{0.f, 0.f, 0.f, 0.f};

    f32x4 xr[2][2][2];
    i32x4 wreg[2];
    const unsigned short* wgp0 = wt1e + r0 * DIM + q0 * 8;
    const unsigned short* wgp1 = wgp0 + 128 * DIM;
    const int abase = L_W + (wn * 128 + l15) * 72 + l4o;

    // prologue: W chunk0 -> buf0; issue W chunk1, X chunks 0,1
    wreg[0] = ld16(wgp0); wreg[1] = ld16(wgp1);
    #pragma unroll
    for (int s = 0; s < 2; ++s)
      #pragma unroll
      for (int mi = 0; mi < 2; ++mi) {
        xr[s][mi][0] = *(const f32x4*)(xp[mi] + s * 32);
        xr[s][mi][1] = *(const f32x4*)(xp[mi] + s * 32 + 4);
      }
    *(i32x4*)(smem + wl0) = wreg[0];
    *(i32x4*)(smem + wl1) = wreg[1];
    wreg[0] = ld16(wgp0 + 32); wreg[1] = ld16(wgp1 + 32);
    __syncthreads();

    #pragma unroll
    for (int kk = 0; kk < 12; ++kk) {
      const int cb = kk & 1;
      bf16x8 bx[2];
      #pragma unroll
      for (int mi = 0; mi < 2; ++mi) {
        bx[mi] = cvt8(xr[cb][mi][0], xr[cb][mi][1]);
        if (kk + 2 < 12) {
          xr[cb][mi][0] = *(const f32x4*)(xp[mi] + (kk + 2) * 32);
          xr[cb][mi][1] = *(const f32x4*)(xp[mi] + (kk + 2) * 32 + 4);
        }
      }
      #pragma unroll
      for (int nh = 0; nh < 2; ++nh) {
        bf16x8 af[4];
        #pragma unroll
        for (int ni = 0; ni < 4; ++ni)
          af[ni] = *(const bf16x8*)(smem + abase + cb * L_WBUF + (nh * 4 + ni) * 1152);
        #pragma unroll
        for (int ni = 0; ni < 4; ++ni)
          #pragma unroll
          for (int mi = 0; mi < 2; ++mi)
            acc[nh * 4 + ni][mi] = __builtin_amdgcn_mfma_f32_16x16x32_bf16(
                af[ni], bx[mi], acc[nh * 4 + ni][mi], 0, 0, 0);
      }
      if (kk + 1 < 12) {
        *(i32x4*)(smem + wl0 + (cb ^ 1) * L_WBUF) = wreg[0];
        *(i32x4*)(smem + wl1 + (cb ^ 1) * L_WBUF) = wreg[1];
        if (kk + 2 < 12) {
          wreg[0] = ld16(wgp0 + (kk + 2) * 32);
          wreg[1] = ld16(wgp1 + (kk + 2) * 32);
        }
        __syncthreads();
      }
    }
    // epilogue: bias + celu -> h1 (K-major [m][n], stride 528 B)
    #pragma unroll
    for (int ni = 0; ni < 8; ++ni) {
      const int nb = wn * 128 + ni * 16 + r4;
      float4 bias = *(const float4*)(b1g + e * H1N + nb);
      #pragma unroll
      for (int mi = 0; mi < 2; ++mi) {
        const int m = wm * 32 + mi * 16 + l15;
        f32x4 v = acc[ni][mi];
        i32x2 p;
        p.x = (int)pack2(celu1(v.x + bias.x), celu1(v.y + bias.y));
        p.y = (int)pack2(celu1(v.z + bias.z), celu1(v.w + bias.w));
        *(i32x2*)(smem + L_H1 + m * 528 + nb * 2) = p;
      }
    }
  }

  // ================= Layer 2: 256 -> 192 =================
  {
    f32x4 acc[6][2];
    #pragma unroll
    for (int a = 0; a < 6; ++a)
      #pragma unroll
      for (int b = 0; b < 2; ++b)
        acc[a][b] = f32x4{0.f, 0.f, 0.f, 0.f};

    i32x4 wreg[2];
    const bool u1 = (tid < 256);   // rows 128..191
    const unsigned short* wgp0 = wt2e + r0 * H1N + q0 * 8;
    const unsigned short* wgp1 = wgp0 + 128 * H1N;
    const int abase = L_W + (wn * 96 + l15) * 72 + l4o;
    const int hbase = L_H1 + (wm * 32 + l15) * 528 + l4o;

    wreg[0] = ld16(wgp0);
    if (u1) wreg[1] = ld16(wgp1);
    __syncthreads();               // h1 visible; W bufs free
    *(i32x4*)(smem + wl0) = wreg[0];
    if (u1) *(i32x4*)(smem + wl1) = wreg[1];
    wreg[0] = ld16(wgp0 + 32);
    if (u1) wreg[1] = ld16(wgp1 + 32);
    __syncthreads();

    #pragma unroll
    for (int kk = 0; kk < 8; ++kk) {
      const int cb = kk & 1;
      bf16x8 bxh[2];
      #pragma unroll
      for (int mi = 0; mi < 2; ++mi)
        bxh[mi] = *(const bf16x8*)(smem + hbase + mi * 16 * 528 + kk * 64);
      #pragma unroll
      for (int nh = 0; nh < 2; ++nh) {
        bf16x8 af[3];
        #pragma unroll
        for (int ni = 0; ni < 3; ++ni)
          af[ni] = *(const bf16x8*)(smem + abase + cb * L_WBUF + (nh * 3 + ni) * 1152);
        #pragma unroll
        for (int ni = 0; ni < 3; ++ni)
          #pragma unroll
          for (int mi = 0; mi < 2; ++mi)
            acc[nh * 3 + ni][mi] = __builtin_amdgcn_mfma_f32_16x16x32_bf16(
                af[ni], bxh[mi], acc[nh * 3 + ni][mi], 0, 0, 0);
      }
      if (kk + 1 < 8) {
        *(i32x4*)(smem + wl0 + (cb ^ 1) * L_WBUF) = wreg[0];
        if (u1) *(i32x4*)(smem + wl1 + (cb ^ 1) * L_WBUF) = wreg[1];
        if (kk + 2 < 8) {
          wreg[0] = ld16(wgp0 + (kk + 2) * 32);
          if (u1) wreg[1] = ld16(wgp1 + (kk + 2) * 32);
        }
        __syncthreads();
      }
    }
    #pragma unroll
    for (int ni = 0; ni < 6; ++ni) {
      const int nb = wn * 96 + ni * 16 + r4;
      float4 bias = *(const float4*)(b2g + e * H2N + nb);
      #pragma unroll
      for (int mi = 0; mi < 2; ++mi) {
        const int m = wm * 32 + mi * 16 + l15;
        f32x4 v = acc[ni][mi];
        i32x2 p;
        p.x = (int)pack2(celu1(v.x + bias.x), celu1(v.y + bias.y));
        p.y = (int)pack2(celu1(v.z + bias.z), celu1(v.w + bias.w));
        *(i32x2*)(smem + L_H2 + m * 400 + nb * 2) = p;
      }
    }
  }

  // ================= Layer 3: 192 -> 160 =================
  {
    f32x4 acc[5][2];
    #pragma unroll
    for (int a = 0; a < 5; ++a)
      #pragma unroll
      for (int b = 0; b < 2; ++b)
        acc[a][b] = f32x4{0.f, 0.f, 0.f, 0.f};

    i32x4 wreg[2];
    const bool u1 = (tid < 128);   // rows 128..159
    const unsigned short* wgp0 = wt3e + r0 * H2N + q0 * 8;
    const unsigned short* wgp1 = wgp0 + 128 * H2N;
    const int abase = L_W + (wn * 80 + l15) * 72 + l4o;
    const int hbase = L_H2 + (wm * 32 + l15) * 400 + l4o;

    wreg[0] = ld16(wgp0);
    if (u1) wreg[1] = ld16(wgp1);
    __syncthreads();               // h2 visible; W bufs free
    *(i32x4*)(smem + wl0) = wreg[0];
    if (u1) *(i32x4*)(smem + wl1) = wreg[1];
    wreg[0] = ld16(wgp0 + 32);
    if (u1) wreg[1] = ld16(wgp1 + 32);
    __syncthreads();

    #pragma unroll
    for (int kk = 0; kk < 6; ++kk) {
      const int cb = kk & 1;
      bf16x8 bxh[2];
      #pragma unroll
      for (int mi = 0; mi < 2; ++mi)
        bxh[mi] = *(const bf16x8*)(smem + hbase + mi * 16 * 400 + kk * 64);
      bf16x8 af[5];
      #pragma unroll
      for (int ni = 0; ni < 5; ++ni)
        af[ni] = *(const bf16x8*)(smem + abase + cb * L_WBUF + ni * 1152);
      #pragma unroll
      for (int ni = 0; ni < 5; ++ni)
        #pragma unroll
        for (int mi = 0; mi < 2; ++mi)
          acc[ni][mi] = __builtin_amdgcn_mfma_f32_16x16x32_bf16(
              af[ni], bxh[mi], acc[ni][mi], 0, 0, 0);
      if (kk + 1 < 6) {
        *(i32x4*)(smem + wl0 + (cb ^ 1) * L_WBUF) = wreg[0];
        if (u1) *(i32x4*)(smem + wl1 + (cb ^ 1) * L_WBUF) = wreg[1];
        if (kk + 2 < 6) {
          wreg[0] = ld16(wgp0 + (kk + 2) * 32);
          if (u1) wreg[1] = ld16(wgp1 + (kk + 2) * 32);
        }
        __syncthreads();
      }
    }
    // epilogue -> h3 in the (now-free) H1 region, stride 336 B
    #pragma unroll
    for (int ni = 0; ni < 5; ++ni) {
      const int nb = wn * 80 + ni * 16 + r4;
      float4 bias = *(const float4*)(b3g + e * H3N + nb);
      #pragma unroll
      for (int mi = 0; mi < 2; ++mi) {
        const int m = wm * 32 + mi * 16 + l15;
        f32x4 v = acc[ni][mi];
        i32x2 p;
        p.x = (int)pack2(celu1(v.x + bias.x), celu1(v.y + bias.y));
        p.y = (int)pack2(celu1(v.z + bias.z), celu1(v.w + bias.w));
        *(i32x2*)(smem + L_H1 + m * 336 + nb * 2) = p;
      }
    }
  }
  __syncthreads();

  // ================= Layer 4: 160 -> 1 (VALU) =================
  {
    const int m = tid >> 2, sub = tid & 3;
    const char* hp = smem + L_H1 + m * 336 + sub * 80;
    const float* wp = w4g + e * H3N + sub * 40;
    float s = 0.f;
    #pragma unroll
    for (int j = 0; j < 5; ++j) {
      i32x4 hv = *(const i32x4*)(hp + j * 16);
      float4 w0 = *(const float4*)(wp + j * 8);
      float4 w1 = *(const float4*)(wp + j * 8 + 4);
      s += __uint_as_float(((unsigned)hv.x) << 16) * w0.x;
      s += __uint_as_float(((unsigned)hv.x) & 0xffff0000u) * w0.y;
      s += __uint_as_float(((unsigned)hv.y) << 16) * w0.z;
      s += __uint_as_float(((unsigned)hv.y) & 0xffff0000u) * w0.w;
      s += __uint_as_float(((unsigned)hv.z) << 16) * w1.x;
      s += __uint_as_float(((unsigned)hv.z) & 0xffff0000u) * w1.y;
      s += __uint_as_float(((unsigned)hv.w) << 16) * w1.z;
      s += __uint_as_float(((unsigned)hv.w) & 0xffff0000u) * w1.w;
    }
    s += __shfl_xor(s, 1);
    s += __shfl_xor(s, 2);
    if (sub == 0 && m < len) {
      float y = (s + b4g[e]) * alpg[e] + shfg[e];
      out[ldsRows[m]] = y;
    }
  }
}

extern "C" void kernel_launch(void* const* d_in, const int* in_sizes, int n_in,
                              void* d_out, int out_size, void* d_ws, size_t ws_size,
                              hipStream_t stream) {
  (void)in_sizes; (void)n_in; (void)out_size; (void)ws_size;
  const float* aev    = (const float*)d_in[0];
  const int*   index  = (const int*)d_in[1];
  const float* W1     = (const float*)d_in[2];
  const float* b1     = (const float*)d_in[3];
  const float* W2     = (const float*)d_in[4];
  const float* b2     = (const float*)d_in[5];
  const float* W3     = (const float*)d_in[6];
  const float* b3     = (const float*)d_in[7];
  const float* W4     = (const float*)d_in[8];
  const float* b4     = (const float*)d_in[9];
  const float* alphas = (const float*)d_in[10];
  const float* shifts = (const float*)d_in[11];
  float* out = (float*)d_out;
  char* ws = (char*)d_ws;

  int*   meta  = (int*)(ws + WS_META);
  i32x4* table = (i32x4*)(ws + WS_TABLE);
  int*   perm  = (int*)(ws + WS_PERM);
  unsigned short* wt1 = (unsigned short*)(ws + WS_WT1);
  unsigned short* wt2 = (unsigned short*)(ws + WS_WT2);
  unsigned short* wt3 = (unsigned short*)(ws + WS_WT3);

  hipFuncSetAttribute((const void*)k_mlp,
                      hipFuncAttributeMaxDynamicSharedMemorySize, LDS_TOTAL);

  k_zero<<<1, 64, 0, stream>>>(meta);
  k_wprep<<<(NE*(H1N*DIM + H2N*H1N + H3N*H2N) + 255) / 256, 256, 0, stream>>>(
      W1, W2, W3, wt1, wt2, wt3);
  k_hist<<<NATOMS/1024, 256, 0, stream>>>(index, meta);
  k_plan<<<1, 256, 0, stream>>>(meta, table);
  k_scatter<<<NATOMS/1024, 256, 0, stream>>>(index, meta, perm);
  k_mlp<<<NTILES, NTH, LDS_TOTAL, stream>>>(
      aev, wt1, wt2, wt3, b1, b2, b3, W4, b4, alphas, shifts, perm, table, out);
}

// Round 3
// 443.480 us; speedup vs baseline: 1.3770x; 1.1932x over previous
//
#include <hip/hip_runtime.h>
#include <hip/hip_bf16.h>

#define NATOMS 131072
#define DIM    384
#define NE     4
#define H1N    256
#define H2N    192
#define H3N    160
#define BM     64
#define NTH    256
#define NTILES (NATOMS/BM + NE)   // 2052

typedef __attribute__((ext_vector_type(8))) short bf16x8;
typedef __attribute__((ext_vector_type(4))) float f32x4;
typedef __attribute__((ext_vector_type(4))) int   i32x4;
typedef __attribute__((ext_vector_type(2))) int   i32x2;

// ---------------- ws layout (bytes) ----------------
#define WS_META   0
#define WS_TABLE  64
#define WS_PERM   (WS_TABLE + NTILES*16)
#define WS_WT1    ((WS_PERM + NATOMS*4 + 255) & ~255)
#define SZ_WT1    (NE*H1N*DIM*2)
#define WS_WT2    (WS_WT1 + SZ_WT1)
#define SZ_WT2    (NE*H2N*H1N*2)
#define WS_WT3    (WS_WT2 + SZ_WT2)
#define SZ_WT3    (NE*H3N*H2N*2)

// ---------------- LDS layout (bytes) ----------------
// Only activations live in LDS. 59.6 KB -> 2 blocks/CU.
#define L_ROWS 0                        // 64 ints = 256 B
#define L_H1   256                      // 64 x 528 B  (also h3: 64 x 336)
#define L_H2   (L_H1 + BM*528)          // 34048: 64 x 400 B
#define LDS_TOTAL (L_H2 + BM*400)       // 59648

static __device__ __forceinline__ unsigned short f2bf(float f) {
  union { __hip_bfloat16 h; unsigned short u; } v;
  v.h = __float2bfloat16(f);
  return v.u;
}
static __device__ __forceinline__ unsigned pack2(float a, float b) {
  union { __hip_bfloat162 h2; unsigned u; } v;
  v.h2 = __float22bfloat162_rn(make_float2(a, b));
  return v.u;
}
static __device__ __forceinline__ float celu1(float x) {
  return x > 0.f ? x : (__expf(x) - 1.f);
}
static __device__ __forceinline__ bf16x8 cvt8(f32x4 a, f32x4 b) {
  union { bf16x8 v; unsigned u[4]; } r;
  r.u[0] = pack2(a.x, a.y); r.u[1] = pack2(a.z, a.w);
  r.u[2] = pack2(b.x, b.y); r.u[3] = pack2(b.z, b.w);
  return r.v;
}

// ---------------- prep kernels ----------------
__global__ void k_zero(int* meta) {
  if (threadIdx.x < 16) meta[threadIdx.x] = 0;
}

// Tile-transpose W[e][k][n] (fp32) -> wt[e][kk][n][32] (bf16, chunk-major).
// Coalesced loads (n-fast) and coalesced stores (k-fast within a 32-chunk).
__global__ void k_wprep(const float* __restrict__ W1, const float* __restrict__ W2,
                        const float* __restrict__ W3,
                        unsigned short* __restrict__ wt1,
                        unsigned short* __restrict__ wt2,
                        unsigned short* __restrict__ wt3) {
  __shared__ float t[32][33];
  int b = blockIdx.x;
  const float* W; unsigned short* wt; int K, NN, ntiles, idx;
  if (b < 384)      { W = W1; wt = wt1; K = 384; NN = 256; ntiles = 8; idx = b; }
  else if (b < 576) { W = W2; wt = wt2; K = 256; NN = 192; ntiles = 6; idx = b - 384; }
  else              { W = W3; wt = wt3; K = 192; NN = 160; ntiles = 5; idx = b - 576; }
  int per_e = (K / 32) * ntiles;
  int e  = idx / per_e;
  int r  = idx % per_e;
  int kt = r / ntiles, nt = r % ntiles;

  int row = threadIdx.x >> 3, c4 = (threadIdx.x & 7) * 4;
  float4 v = *(const float4*)(W + ((size_t)(e * K + kt * 32 + row) * NN + nt * 32 + c4));
  t[row][c4 + 0] = v.x; t[row][c4 + 1] = v.y;
  t[row][c4 + 2] = v.z; t[row][c4 + 3] = v.w;
  __syncthreads();

  int n = threadIdx.x >> 3, k4 = (threadIdx.x & 7) * 4;
  unsigned short o[4];
  o[0] = f2bf(t[k4 + 0][n]); o[1] = f2bf(t[k4 + 1][n]);
  o[2] = f2bf(t[k4 + 2][n]); o[3] = f2bf(t[k4 + 3][n]);
  i32x2 p; p.x = (int)(o[0] | ((unsigned)o[1] << 16));
  p.y = (int)(o[2] | ((unsigned)o[3] << 16));
  *(i32x2*)(wt + ((size_t)(e * (K / 32) + kt) * NN + nt * 32 + n) * 32 + k4) = p;
}

__global__ void k_hist(const int* __restrict__ index, int* __restrict__ meta) {
  __shared__ int h[NE];
  int t = threadIdx.x;
  if (t < NE) h[t] = 0;
  __syncthreads();
  int b0 = blockIdx.x * 1024;
  #pragma unroll
  for (int j = 0; j < 4; ++j) atomicAdd(&h[index[b0 + t + j*256]], 1);
  __syncthreads();
  if (t < NE) atomicAdd(&meta[t], h[t]);
}

__global__ void k_plan(int* __restrict__ meta, i32x4* __restrict__ table) {
  __shared__ int off[NE + 1], nt[NE + 1];
  if (threadIdx.x == 0) {
    int o = 0, t = 0;
    for (int e = 0; e < NE; ++e) {
      off[e] = o; nt[e] = t;
      o += meta[e];
      t += (meta[e] + BM - 1) / BM;
      meta[4 + e] = off[e];
    }
    off[NE] = o; nt[NE] = t;
  }
  __syncthreads();
  for (int i = threadIdx.x; i < NTILES; i += blockDim.x) {
    i32x4 v = {0, 0, 0, 0};
    for (int e = 0; e < NE; ++e) {
      if (i >= nt[e] && i < nt[e + 1]) {
        int local = i - nt[e];
        int cnt = off[e + 1] - off[e];
        int rem = cnt - local * BM;
        v.x = e; v.y = off[e] + local * BM; v.z = rem < BM ? rem : BM;
      }
    }
    table[i] = v;
  }
}

__global__ void k_scatter(const int* __restrict__ index, int* __restrict__ meta,
                          int* __restrict__ perm) {
  __shared__ int h[NE], base[NE];
  int t = threadIdx.x;
  if (t < NE) h[t] = 0;
  __syncthreads();
  int b0 = blockIdx.x * 1024;
  int eIdx[4];
  #pragma unroll
  for (int j = 0; j < 4; ++j) {
    eIdx[j] = index[b0 + t + j*256];
    atomicAdd(&h[eIdx[j]], 1);
  }
  __syncthreads();
  if (t < NE) { base[t] = atomicAdd(&meta[4 + t], h[t]); h[t] = 0; }
  __syncthreads();
  #pragma unroll
  for (int j = 0; j < 4; ++j) {
    int e = eIdx[j];
    int slot = atomicAdd(&h[e], 1);
    perm[base[e] + slot] = b0 + t + j*256;
  }
}

// ---------------- fused MLP ----------------
// y^T = W^T x^T. 4 waves = 2 n-groups x 2 m-groups, 64 atoms/block.
// NO barriers inside K-loops: weights are read per-wave straight from the
// chunk-major wt buffers (L1/L2-hot), X per-lane from aev with 3-deep
// register prefetch. Barriers only at layer boundaries (4 total).
__launch_bounds__(NTH, 2)
__global__ void k_mlp(const float* __restrict__ aev,
                      const unsigned short* __restrict__ wt1,
                      const unsigned short* __restrict__ wt2,
                      const unsigned short* __restrict__ wt3,
                      const float* __restrict__ b1g,
                      const float* __restrict__ b2g,
                      const float* __restrict__ b3g,
                      const float* __restrict__ w4g,
                      const float* __restrict__ b4g,
                      const float* __restrict__ alpg,
                      const float* __restrict__ shfg,
                      const int* __restrict__ perm,
                      const i32x4* __restrict__ table,
                      float* __restrict__ out)
{
  extern __shared__ char smem[];
  int* ldsRows = (int*)(smem + L_ROWS);

  i32x4 tt = table[blockIdx.x];
  const int e = tt.x, start = tt.y, len = tt.z;
  if (len == 0) return;

  const int tid = threadIdx.x;
  const int l   = tid & 63;
  const int w   = tid >> 6;
  const int l15 = l & 15;
  const int lg  = l >> 4;
  const int l4o = lg * 16;
  const int r4  = lg * 4;
  const int wn  = w & 1;    // n-half
  const int wm  = w >> 1;   // m-half (32 atoms, 2 m-frags)

  if (tid < BM) ldsRows[tid] = (tid < len) ? perm[start + tid] : -1;

  // per-lane aev row pointers for this wave's 2 m-fragments
  const float* xp[2];
  #pragma unroll
  for (int mi = 0; mi < 2; ++mi) {
    int row = wm * 32 + mi * 16 + l15;
    int ar = (row < len) ? perm[start + row] : 0;
    xp[mi] = aev + (size_t)ar * DIM + lg * 8;
  }

  // ================= Layer 1: 384 -> 256 =================
  {
    f32x4 acc[8][2];
    #pragma unroll
    for (int a = 0; a < 8; ++a)
      #pragma unroll
      for (int b = 0; b < 2; ++b)
        acc[a][b] = f32x4{0.f, 0.f, 0.f, 0.f};

    const unsigned short* w1base =
        wt1 + (size_t)e * (12 * 256 * 32) + (wn * 128 + l15) * 32 + lg * 8;

    bf16x8 af[2][8];
    f32x4  xr[3][2][2];
    // prologue: X 3-deep, W 1-deep
    #pragma unroll
    for (int s = 0; s < 3; ++s)
      #pragma unroll
      for (int mi = 0; mi < 2; ++mi) {
        xr[s][mi][0] = *(const f32x4*)(xp[mi] + s * 32);
        xr[s][mi][1] = *(const f32x4*)(xp[mi] + s * 32 + 4);
      }
    #pragma unroll
    for (int ni = 0; ni < 8; ++ni)
      af[0][ni] = *(const bf16x8*)(w1base + ni * 512);

    #pragma unroll
    for (int kk = 0; kk < 12; ++kk) {
      const int cb = kk & 1, xb = kk % 3;
      if (kk + 1 < 12) {
        #pragma unroll
        for (int ni = 0; ni < 8; ++ni)
          af[cb ^ 1][ni] = *(const bf16x8*)(w1base + (kk + 1) * 8192 + ni * 512);
      }
      bf16x8 bx[2];
      #pragma unroll
      for (int mi = 0; mi < 2; ++mi) {
        bx[mi] = cvt8(xr[xb][mi][0], xr[xb][mi][1]);
        if (kk + 3 < 12) {
          xr[xb][mi][0] = *(const f32x4*)(xp[mi] + (kk + 3) * 32);
          xr[xb][mi][1] = *(const f32x4*)(xp[mi] + (kk + 3) * 32 + 4);
        }
      }
      #pragma unroll
      for (int ni = 0; ni < 8; ++ni)
        #pragma unroll
        for (int mi = 0; mi < 2; ++mi)
          acc[ni][mi] = __builtin_amdgcn_mfma_f32_16x16x32_bf16(
              af[cb][ni], bx[mi], acc[ni][mi], 0, 0, 0);
    }
    // epilogue: bias + celu -> h1 (K-major [m][n], stride 528 B)
    #pragma unroll
    for (int ni = 0; ni < 8; ++ni) {
      const int nb = wn * 128 + ni * 16 + r4;
      float4 bias = *(const float4*)(b1g + e * H1N + nb);
      #pragma unroll
      for (int mi = 0; mi < 2; ++mi) {
        const int m = wm * 32 + mi * 16 + l15;
        f32x4 v = acc[ni][mi];
        i32x2 p;
        p.x = (int)pack2(celu1(v.x + bias.x), celu1(v.y + bias.y));
        p.y = (int)pack2(celu1(v.z + bias.z), celu1(v.w + bias.w));
        *(i32x2*)(smem + L_H1 + m * 528 + nb * 2) = p;
      }
    }
  }
  __syncthreads();   // h1 visible

  // ================= Layer 2: 256 -> 192 =================
  {
    f32x4 acc[6][2];
    #pragma unroll
    for (int a = 0; a < 6; ++a)
      #pragma unroll
      for (int b = 0; b < 2; ++b)
        acc[a][b] = f32x4{0.f, 0.f, 0.f, 0.f};

    const unsigned short* w2base =
        wt2 + (size_t)e * (8 * 192 * 32) + (wn * 96 + l15) * 32 + lg * 8;
    const int hbase = L_H1 + (wm * 32 + l15) * 528 + l4o;

    bf16x8 af[2][6];
    #pragma unroll
    for (int ni = 0; ni < 6; ++ni)
      af[0][ni] = *(const bf16x8*)(w2base + ni * 512);

    #pragma unroll
    for (int kk = 0; kk < 8; ++kk) {
      const int cb = kk & 1;
      if (kk + 1 < 8) {
        #pragma unroll
        for (int ni = 0; ni < 6; ++ni)
          af[cb ^ 1][ni] = *(const bf16x8*)(w2base + (kk + 1) * 6144 + ni * 512);
      }
      bf16x8 bxh[2];
      #pragma unroll
      for (int mi = 0; mi < 2; ++mi)
        bxh[mi] = *(const bf16x8*)(smem + hbase + mi * 16 * 528 + kk * 64);
      #pragma unroll
      for (int ni = 0; ni < 6; ++ni)
        #pragma unroll
        for (int mi = 0; mi < 2; ++mi)
          acc[ni][mi] = __builtin_amdgcn_mfma_f32_16x16x32_bf16(
              af[cb][ni], bxh[mi], acc[ni][mi], 0, 0, 0);
    }
    #pragma unroll
    for (int ni = 0; ni < 6; ++ni) {
      const int nb = wn * 96 + ni * 16 + r4;
      float4 bias = *(const float4*)(b2g + e * H2N + nb);
      #pragma unroll
      for (int mi = 0; mi < 2; ++mi) {
        const int m = wm * 32 + mi * 16 + l15;
        f32x4 v = acc[ni][mi];
        i32x2 p;
        p.x = (int)pack2(celu1(v.x + bias.x), celu1(v.y + bias.y));
        p.y = (int)pack2(celu1(v.z + bias.z), celu1(v.w + bias.w));
        *(i32x2*)(smem + L_H2 + m * 400 + nb * 2) = p;
      }
    }
  }
  __syncthreads();   // h2 visible

  // ================= Layer 3: 192 -> 160 =================
  {
    f32x4 acc[5][2];
    #pragma unroll
    for (int a = 0; a < 5; ++a)
      #pragma unroll
      for (int b = 0; b < 2; ++b)
        acc[a][b] = f32x4{0.f, 0.f, 0.f, 0.f};

    const unsigned short* w3base =
        wt3 + (size_t)e * (6 * 160 * 32) + (wn * 80 + l15) * 32 + lg * 8;
    const int hbase = L_H2 + (wm * 32 + l15) * 400 + l4o;

    bf16x8 af[2][5];
    #pragma unroll
    for (int ni = 0; ni < 5; ++ni)
      af[0][ni] = *(const bf16x8*)(w3base + ni * 512);

    #pragma unroll
    for (int kk = 0; kk < 6; ++kk) {
      const int cb = kk & 1;
      if (kk + 1 < 6) {
        #pragma unroll
        for (int ni = 0; ni < 5; ++ni)
          af[cb ^ 1][ni] = *(const bf16x8*)(w3base + (kk + 1) * 5120 + ni * 512);
      }
      bf16x8 bxh[2];
      #pragma unroll
      for (int mi = 0; mi < 2; ++mi)
        bxh[mi] = *(const bf16x8*)(smem + hbase + mi * 16 * 400 + kk * 64);
      #pragma unroll
      for (int ni = 0; ni < 5; ++ni)
        #pragma unroll
        for (int mi = 0; mi < 2; ++mi)
          acc[ni][mi] = __builtin_amdgcn_mfma_f32_16x16x32_bf16(
              af[cb][ni], bxh[mi], acc[ni][mi], 0, 0, 0);
    }
    // epilogue -> h3 in the (now-free) H1 region, stride 336 B
    #pragma unroll
    for (int ni = 0; ni < 5; ++ni) {
      const int nb = wn * 80 + ni * 16 + r4;
      float4 bias = *(const float4*)(b3g + e * H3N + nb);
      #pragma unroll
      for (int mi = 0; mi < 2; ++mi) {
        const int m = wm * 32 + mi * 16 + l15;
        f32x4 v = acc[ni][mi];
        i32x2 p;
        p.x = (int)pack2(celu1(v.x + bias.x), celu1(v.y + bias.y));
        p.y = (int)pack2(celu1(v.z + bias.z), celu1(v.w + bias.w));
        *(i32x2*)(smem + L_H1 + m * 336 + nb * 2) = p;
      }
    }
  }
  __syncthreads();   // h3 + ldsRows visible

  // ================= Layer 4: 160 -> 1 (VALU) =================
  {
    const int m = tid >> 2, sub = tid & 3;   // 4 lanes per atom, 64 atoms
    const char* hp = smem + L_H1 + m * 336 + sub * 80;
    const float* wp = w4g + e * H3N + sub * 40;
    float s = 0.f;
    #pragma unroll
    for (int j = 0; j < 5; ++j) {
      i32x4 hv = *(const i32x4*)(hp + j * 16);
      float4 w0 = *(const float4*)(wp + j * 8);
      float4 w1 = *(const float4*)(wp + j * 8 + 4);
      s += __uint_as_float(((unsigned)hv.x) << 16) * w0.x;
      s += __uint_as_float(((unsigned)hv.x) & 0xffff0000u) * w0.y;
      s += __uint_as_float(((unsigned)hv.y) << 16) * w0.z;
      s += __uint_as_float(((unsigned)hv.y) & 0xffff0000u) * w0.w;
      s += __uint_as_float(((unsigned)hv.z) << 16) * w1.x;
      s += __uint_as_float(((unsigned)hv.z) & 0xffff0000u) * w1.y;
      s += __uint_as_float(((unsigned)hv.w) << 16) * w1.z;
      s += __uint_as_float(((unsigned)hv.w) & 0xffff0000u) * w1.w;
    }
    s += __shfl_xor(s, 1);
    s += __shfl_xor(s, 2);
    if (sub == 0 && m < len) {
      float y = (s + b4g[e]) * alpg[e] + shfg[e];
      out[ldsRows[m]] = y;
    }
  }
}

extern "C" void kernel_launch(void* const* d_in, const int* in_sizes, int n_in,
                              void* d_out, int out_size, void* d_ws, size_t ws_size,
                              hipStream_t stream) {
  (void)in_sizes; (void)n_in; (void)out_size; (void)ws_size;
  const float* aev    = (const float*)d_in[0];
  const int*   index  = (const int*)d_in[1];
  const float* W1     = (const float*)d_in[2];
  const float* b1     = (const float*)d_in[3];
  const float* W2     = (const float*)d_in[4];
  const float* b2     = (const float*)d_in[5];
  const float* W3     = (const float*)d_in[6];
  const float* b3     = (const float*)d_in[7];
  const float* W4     = (const float*)d_in[8];
  const float* b4     = (const float*)d_in[9];
  const float* alphas = (const float*)d_in[10];
  const float* shifts = (const float*)d_in[11];
  float* out = (float*)d_out;
  char* ws = (char*)d_ws;

  int*   meta  = (int*)(ws + WS_META);
  i32x4* table = (i32x4*)(ws + WS_TABLE);
  int*   perm  = (int*)(ws + WS_PERM);
  unsigned short* wt1 = (unsigned short*)(ws + WS_WT1);
  unsigned short* wt2 = (unsigned short*)(ws + WS_WT2);
  unsigned short* wt3 = (unsigned short*)(ws + WS_WT3);

  k_zero<<<1, 64, 0, stream>>>(meta);
  k_wprep<<<696, 256, 0, stream>>>(W1, W2, W3, wt1, wt2, wt3);
  k_hist<<<NATOMS/1024, 256, 0, stream>>>(index, meta);
  k_plan<<<1, 256, 0, stream>>>(meta, table);
  k_scatter<<<NATOMS/1024, 256, 0, stream>>>(index, meta, perm);
  k_mlp<<<NTILES, NTH, LDS_TOTAL, stream>>>(
      aev, wt1, wt2, wt3, b1, b2, b3, W4, b4, alphas, shifts, perm, table, out);
}